// Round 10
// baseline (185.571 us; speedup 1.0000x reference)
//
#include <hip/hip_runtime.h>
#include <hip/hip_bf16.h>
#include <stdint.h>

typedef __bf16 bf16;
typedef __attribute__((ext_vector_type(8))) __bf16 bf16x8;
typedef __attribute__((ext_vector_type(4))) float f32x4;

typedef __attribute__((address_space(3))) char* lds_ptr;
typedef const __attribute__((address_space(1))) char* glb_ptr;

#define BZ 4
#define NN 2048
#define CC 1024

__device__ __forceinline__ void gload_lds16(const bf16* g, bf16* l) {
    __builtin_amdgcn_global_load_lds((glb_ptr)g, (lds_ptr)l, 16, 0, 0);
}

__device__ __forceinline__ void bar() {
    asm volatile("" ::: "memory");
    __builtin_amdgcn_s_barrier();
    asm volatile("" ::: "memory");
}

// -------- fp32 -> bf16 convert, both inputs in one dispatch (8 elems/thr) --------
__global__ void cvt2_f32_bf16(const float* __restrict__ a, const float* __restrict__ b,
                              bf16* __restrict__ oa, bf16* __restrict__ ob, int n8) {
    int i = blockIdx.x * blockDim.x + threadIdx.x;
    if (i >= 2 * n8) return;
    const float4* p;
    bf16* dst;
    int j;
    if (i < n8) { p = (const float4*)a; dst = oa; j = i; }
    else        { p = (const float4*)b; dst = ob; j = i - n8; }
    float4 x = p[2 * j], y = p[2 * j + 1];
    bf16x8 o;
    o[0] = (bf16)x.x; o[1] = (bf16)x.y; o[2] = (bf16)x.z; o[3] = (bf16)x.w;
    o[4] = (bf16)y.x; o[5] = (bf16)y.y; o[6] = (bf16)y.z; o[7] = (bf16)y.w;
    *(bf16x8*)(dst + 8 * (size_t)j) = o;
}

// ------- all three W [C][C] f32 -> [d][c] bf16 transposed, z-indexed -------
__global__ void transposeW3(const float* __restrict__ W0, const float* __restrict__ W1,
                            const float* __restrict__ W2, bf16* __restrict__ T0,
                            bf16* __restrict__ T1, bf16* __restrict__ T2) {
    __shared__ bf16 t[32][33];
    const int z = blockIdx.z;
    const float* W = z == 0 ? W0 : (z == 1 ? W1 : W2);
    bf16* Wt = z == 0 ? T0 : (z == 1 ? T1 : T2);
    int d0 = blockIdx.x * 32, c0 = blockIdx.y * 32;
    int tx = threadIdx.x, ty = threadIdx.y;  // 32x8
#pragma unroll
    for (int i = 0; i < 4; i++)
        t[ty + 8 * i][tx] = (bf16)W[(size_t)(c0 + ty + 8 * i) * CC + d0 + tx];
    __syncthreads();
#pragma unroll
    for (int i = 0; i < 4; i++)
        Wt[(size_t)(d0 + ty + 8 * i) * CC + c0 + tx] = t[tx][ty + 8 * i];
}

// ------- bq|bk concat + zero the softmax row-sum accumulator (every call) -------
__global__ void prep(const float* __restrict__ a, const float* __restrict__ b,
                     float* __restrict__ bqk, float* __restrict__ rowsum) {
    int i = blockIdx.x * blockDim.x + threadIdx.x;  // 8192 = BZ*NN
    rowsum[i] = 0.f;
    if (i < CC) bqk[i] = a[i];
    else if (i < 2 * CC) bqk[i] = b[i - CC];
}

// ================= 256xBN bf16 B^T GEMM =================
// C[m][n] = scale * sum_k A[m][k]*Bt[n][k]  (+ epilogue op)
// EPI: 0 none; 1 col-bias aux[bz*sAux+col]; 2 row-bias aux[row];
//      3 softmax-numerator: C=exp(s-6) bf16 + f32 row-sum atomics aux[bz*sAux+row];
//      4 row-scale: C = s / aux[bz*sAux+row]  (PV normalize).
// 512 threads = 8 waves (2M x 4N), per-wave 128 x BN/4 output, BK=64.
// BN=256 (QK): NB=2 buffers, 128KB LDS, r8-proven region-recycle schedule.
// BN=128 (projQK/VT/PV): NB=3 buffers, 144KB LDS, DEEP prefetch -- the whole
//   of tile kt+2 is staged during tile kt (A0@P0,A1@P1,B0@P2,B1@P3), giving
//   each load a full-tile (~4-8 phase) lead >= HBM latency; vmcnt(6) at tile
//   end drains exactly tile kt+1; region safety trivial (distinct buffer).

#define STAGE_A(kt_, hh_)                                                        \
    do {                                                                         \
        int _kt = (kt_);                                                         \
        if (_kt < nkt) {                                                         \
            const bf16* _s = gAs + (size_t)((hh_)*128) * lda + (size_t)_kt * 64; \
            bf16* _d = &LA[_kt % NB][((hh_)*128 + wid * 16) * 64];               \
            gload_lds16(_s, _d);                                                 \
            gload_lds16(_s + (size_t)8 * lda, _d + 8 * 64);                      \
        }                                                                        \
    } while (0)

#define STAGE_B(kt_, hh_)                                                          \
    do {                                                                           \
        int _kt = (kt_);                                                           \
        if (_kt < nkt) {                                                           \
            const bf16* _s = gBs + (size_t)((hh_) * (BN / 2)) * ldb +              \
                             (size_t)_kt * 64;                                     \
            bf16* _d = &LB[_kt % NB][((hh_) * (BN / 2) + wid * (BN / 16)) * 64];   \
            gload_lds16(_s, _d);                                                   \
            if (NJ == 2) gload_lds16(_s + (size_t)8 * ldb, _d + 8 * 64);           \
        }                                                                          \
    } while (0)

#define LDA_FRAG(buf_, mh_)                                                      \
    do {                                                                         \
        _Pragma("unroll") for (int _i = 0; _i < 4; ++_i)                         \
            _Pragma("unroll") for (int _ks = 0; _ks < 2; ++_ks)                  \
                a[_i][_ks] = *(const bf16x8*)&LA[buf_][                          \
                    (wm + (mh_)*64 + _i * 16 + fr) * 64 +                        \
                    (((_ks * 4 + hi) ^ lo) * 8)];                                \
    } while (0)

#define LDB_FRAG(buf_, nh_, dst_)                                                \
    do {                                                                         \
        _Pragma("unroll") for (int _j = 0; _j < NJ; ++_j)                        \
            _Pragma("unroll") for (int _ks = 0; _ks < 2; ++_ks)                  \
                dst_[_j][_ks] = *(const bf16x8*)&LB[buf_][                       \
                    (wn + (nh_) * (NJ * 16) + _j * 16 + fr) * 64 +               \
                    (((_ks * 4 + hi) ^ lo) * 8)];                                \
    } while (0)

#define MMQ(mh_, nh_, b_)                                                        \
    do {                                                                         \
        __builtin_amdgcn_s_setprio(1);                                           \
        _Pragma("unroll") for (int _i = 0; _i < 4; ++_i)                         \
            _Pragma("unroll") for (int _j = 0; _j < NJ; ++_j)                    \
                _Pragma("unroll") for (int _ks = 0; _ks < 2; ++_ks)              \
                    acc[(mh_)*4 + _i][(nh_)*NJ + _j] =                           \
                        __builtin_amdgcn_mfma_f32_16x16x32_bf16(                 \
                            a[_i][_ks], b_[_j][_ks],                             \
                            acc[(mh_)*4 + _i][(nh_)*NJ + _j], 0, 0, 0);          \
        __builtin_amdgcn_s_setprio(0);                                           \
    } while (0)

#define VMW(n_) asm volatile("s_waitcnt vmcnt(" #n_ ")" ::: "memory")

template <int BN, int EPI, bool OUT_F32>
__global__ __launch_bounds__(512, 2) void gemm8(
    const bf16* __restrict__ A, int lda,
    const bf16* __restrict__ Bt, int ldb,
    void* __restrict__ Cout, int ldc,
    float* __restrict__ aux, long long sAux, float scale,
    long long sA, long long sB, long long sC, int nkt) {
    constexpr int NJ = BN / 128;
    constexpr int NB = (BN == 128) ? 3 : 2;  // buffers: deep prefetch where LDS fits
    __shared__ __align__(16) bf16 LA[NB][256 * 64];
    __shared__ __align__(16) bf16 LB[NB][BN * 64];

    // ---- XCD-chunked bijective swizzle (m204)
    const int nx = gridDim.x, ny = gridDim.y;
    const int nwg = nx * ny * gridDim.z;
    const int orig = blockIdx.x + nx * (blockIdx.y + ny * blockIdx.z);
    const int q = nwg >> 3, r = nwg & 7;
    const int xcd = orig & 7, land = orig >> 3;
    const int swz = (xcd < r ? xcd * (q + 1) : r * (q + 1) + (xcd - r) * q) + land;
    const int bx = swz % nx;
    const int tmp = swz / nx;
    const int by = tmp % ny, bz = tmp / ny;

    A += (size_t)bz * sA;
    Bt += (size_t)bz * sB;
    const int m0 = by * 256, n0 = bx * BN;
    const int t = threadIdx.x, wid = t >> 6, lane = t & 63;
    const int wm = (wid >> 2) * 128, wn = (wid & 3) * (BN / 4);
    const int fr = lane & 15, hi = lane >> 4, lo = lane & 7;
    f32x4 acc[8][2 * NJ] = {};

    // staging lane geometry: per gload, wave covers 8 rows x 8 chunks of 16B;
    // source chunk pre-swizzled (chunk ^= row&7), LDS dest linear.
    const int srow = lane >> 3;
    const int schunk = lo ^ srow;
    const bf16* gAs = A + (size_t)(m0 + wid * 16 + srow) * lda + schunk * 8;
    const bf16* gBs = Bt + (size_t)(n0 + wid * (BN / 16) + srow) * ldb + schunk * 8;

    if (NB == 3) {
        // prologue: tiles 0 and 1 fully (6 loads each, order A0,A1,B0,B1)
        STAGE_A(0, 0); STAGE_A(0, 1); STAGE_B(0, 0); STAGE_B(0, 1);
        STAGE_A(1, 0); STAGE_A(1, 1); STAGE_B(1, 0); STAGE_B(1, 1);
        VMW(6);  // tile0 landed; tile1's 6 loads in flight
    } else {
        // prologue: tile0 fully + tile1 B0,A0,B1; A1(1) comes at kt=0 P0
        STAGE_A(0, 0); STAGE_A(0, 1); STAGE_B(0, 0); STAGE_B(0, 1);
        STAGE_B(1, 0); STAGE_A(1, 0); STAGE_B(1, 1);
        VMW(6);  // tile0 landed, 3 half-tiles in flight
    }
    bar();

    bf16x8 a[4][2], b0[NJ][2], b1[NJ][2];
    for (int kt = 0; kt < nkt; ++kt) {
        const int buf = kt % NB;
        if (NB == 3) {
            // deep pipeline: stage ALL of tile kt+2 this tile (distinct buffer)
            LDA_FRAG(buf, 0);
            LDB_FRAG(buf, 0, b0);
            STAGE_A(kt + 2, 0);
            MMQ(0, 0, b0);
            bar();
            LDB_FRAG(buf, 1, b1);
            STAGE_A(kt + 2, 1);
            MMQ(0, 1, b1);
            bar();
            LDA_FRAG(buf, 1);
            STAGE_B(kt + 2, 0);
            MMQ(1, 1, b1);
            bar();
            STAGE_B(kt + 2, 1);
            MMQ(1, 0, b0);
            if (kt + 2 < nkt) VMW(6);  // drain tile kt+1 (issued during kt-1)
            else VMW(0);
            bar();
        } else {
            // r8-proven region-recycle schedule (BN=256)
            LDA_FRAG(buf, 0);
            LDB_FRAG(buf, 0, b0);
            STAGE_A(kt + 1, 1);
            MMQ(0, 0, b0);
            bar();
            LDB_FRAG(buf, 1, b1);
            MMQ(0, 1, b1);
            bar();
            LDA_FRAG(buf, 1);
            STAGE_B(kt + 2, 0);
            MMQ(1, 1, b1);
            bar();
            STAGE_A(kt + 2, 0);
            STAGE_B(kt + 2, 1);
            MMQ(1, 0, b0);
            if (kt + 2 < nkt) VMW(6);
            else VMW(0);
            bar();
        }
    }

    // epilogue: C write (C/D map: col=lane&15, row=(lane>>4)*4+reg)
    const int rq = hi * 4;
#pragma unroll
    for (int mh = 0; mh < 2; mh++)
#pragma unroll
        for (int i = 0; i < 4; i++) {
            const int row = m0 + wm + mh * 64 + i * 16 + rq;
            float rsum[4] = {0.f, 0.f, 0.f, 0.f};
            float inv[4];
            if (EPI == 4) {
#pragma unroll
                for (int rr = 0; rr < 4; rr++)
                    inv[rr] = 1.f / aux[bz * sAux + row + rr];
            }
#pragma unroll
            for (int nh = 0; nh < 2; nh++)
#pragma unroll
                for (int j = 0; j < NJ; j++) {
                    int col = n0 + wn + nh * (NJ * 16) + j * 16 + fr;
                    float bb = (EPI == 1) ? aux[bz * sAux + col] : 0.f;
                    f32x4 v = acc[mh * 4 + i][nh * NJ + j];
#pragma unroll
                    for (int rr = 0; rr < 4; rr++) {
                        float o = v[rr] * scale + bb;
                        if (EPI == 2) o += aux[row + rr];
                        if (EPI == 3) { o = __expf(o - 6.f); rsum[rr] += o; }
                        if (EPI == 4) o *= inv[rr];
                        if (OUT_F32)
                            ((float*)Cout)[(size_t)bz * sC + (size_t)(row + rr) * ldc + col] = o;
                        else
                            ((bf16*)Cout)[(size_t)bz * sC + (size_t)(row + rr) * ldc + col] = (bf16)o;
                    }
                }
            if (EPI == 3) {
                // reduce the 64-col partial over the 16 fr-lanes, then one
                // f32 atomic per row per wave.
#pragma unroll
                for (int rr = 0; rr < 4; rr++) {
                    float s = rsum[rr];
                    s += __shfl_xor(s, 1);
                    s += __shfl_xor(s, 2);
                    s += __shfl_xor(s, 4);
                    s += __shfl_xor(s, 8);
                    if (fr == 0) atomicAdd(&aux[bz * sAux + row + rr], s);
                }
            }
        }
}

extern "C" void kernel_launch(void* const* d_in, const int* in_sizes, int n_in,
                              void* d_out, int out_size, void* d_ws, size_t ws_size,
                              hipStream_t stream) {
    const float* event_f = (const float*)d_in[0];
    const float* img_f   = (const float*)d_in[1];
    const float* Wq = (const float*)d_in[2];
    const float* bq = (const float*)d_in[3];
    const float* Wk = (const float*)d_in[4];
    const float* bk = (const float*)d_in[5];
    const float* Wv = (const float*)d_in[6];
    const float* bv = (const float*)d_in[7];
    float* out = (float*)d_out;

    bf16* ws = (bf16*)d_ws;
    const size_t MC = (size_t)BZ * NN * CC;   // 8388608
    const size_t CCsq = (size_t)CC * CC;      // 1048576
    // layout (bf16 elements); S aliases Ebf+Ibf (dead after VT-GEMM)
    bf16* Ebf  = ws;                          // MC
    bf16* Ibf  = ws + MC;                     // MC
    bf16* S    = ws;                          // 2*MC (reuses Ebf+Ibf)
    size_t off = 2 * MC;
    bf16* Wqkt = ws + off; off += 2 * CCsq;   // Wqt | Wkt contiguous
    bf16* Wvt  = ws + off; off += CCsq;
    bf16* Qb   = ws + off; off += MC;         // [8192][1024]
    bf16* Kb   = ws + off; off += MC;         // [8192][1024]
    bf16* VT   = ws + off; off += MC;         // [B][1024][2048]
    float* bqk = (float*)(ws + off);          // 2048 f32
    float* rowsum = bqk + 2 * CC;             // BZ*NN f32 softmax denominators

    // 1. convert both inputs to bf16 (one dispatch)
    {
        int n8 = (int)(MC / 8);
        cvt2_f32_bf16<<<dim3((2 * n8 + 255) / 256), dim3(256), 0, stream>>>(
            event_f, img_f, Ebf, Ibf, n8);
    }
    // 2. transpose all three weights (one dispatch); concat bq|bk + zero rowsum
    transposeW3<<<dim3(CC / 32, CC / 32, 3), dim3(32, 8), 0, stream>>>(
        Wq, Wk, Wv, Wqkt, Wqkt + CCsq, Wvt);
    prep<<<dim3(BZ * NN / 256), dim3(256), 0, stream>>>(bq, bk, bqk, rowsum);
    // 3. fused Q/K projections: z=0 -> Ebf@Wqt+bq -> Qb; z=1 -> Ibf@Wkt+bk -> Kb
    gemm8<128, 1, false><<<dim3(CC / 128, (BZ * NN) / 256, 2), dim3(512), 0, stream>>>(
        Ebf, CC, Wqkt, CC, Qb, CC, bqk, CC, 1.f,
        (long long)MC, (long long)CCsq, (long long)MC, CC / 64);
    // 4. VT = Wv^T @ img^T + bv (row-bias): per batch M=1024, N=2048, K=1024
    gemm8<128, 2, false><<<dim3(NN / 128, CC / 256, BZ), dim3(512), 0, stream>>>(
        Wvt, CC, Ibf, CC, VT, NN, (float*)bv, 0, 1.f,
        0, (long long)NN * CC, (long long)CC * NN, CC / 64);
    // 5. S = exp(Q@K^T/32 - 6) + row-sum atomics (softmax fused, max-free)
    gemm8<256, 3, false><<<dim3(NN / 256, NN / 256, BZ), dim3(512), 0, stream>>>(
        Qb, CC, Kb, CC, S, NN, rowsum, NN, 1.f / 32.f,
        (long long)NN * CC, (long long)NN * CC, (long long)NN * NN, CC / 64);
    // 6. out = (S @ V) / rowsum  (per batch 2048x1024, K=2048) -> fp32
    gemm8<128, 4, true><<<dim3(CC / 128, NN / 256, BZ), dim3(512), 0, stream>>>(
        S, NN, VT, NN, out, CC, rowsum, NN, 1.f,
        (long long)NN * NN, (long long)CC * NN, (long long)NN * CC, NN / 64);
}

// Round 11
// 167.458 us; speedup vs baseline: 1.1082x; 1.1082x over previous
//
#include <hip/hip_runtime.h>
#include <hip/hip_bf16.h>
#include <stdint.h>

typedef __bf16 bf16;
typedef __attribute__((ext_vector_type(8))) __bf16 bf16x8;
typedef __attribute__((ext_vector_type(4))) float f32x4;

typedef __attribute__((address_space(3))) char* lds_ptr;
typedef const __attribute__((address_space(1))) char* glb_ptr;

#define BZ 4
#define NN 2048
#define CC 1024

__device__ __forceinline__ void gload_lds16(const bf16* g, bf16* l) {
    __builtin_amdgcn_global_load_lds((glb_ptr)g, (lds_ptr)l, 16, 0, 0);
}

__device__ __forceinline__ void bar() {
    asm volatile("" ::: "memory");
    __builtin_amdgcn_s_barrier();
    asm volatile("" ::: "memory");
}

// -------- fp32 -> bf16 convert, both inputs in one dispatch (8 elems/thr) --------
__global__ void cvt2_f32_bf16(const float* __restrict__ a, const float* __restrict__ b,
                              bf16* __restrict__ oa, bf16* __restrict__ ob, int n8) {
    int i = blockIdx.x * blockDim.x + threadIdx.x;
    if (i >= 2 * n8) return;
    const float4* p;
    bf16* dst;
    int j;
    if (i < n8) { p = (const float4*)a; dst = oa; j = i; }
    else        { p = (const float4*)b; dst = ob; j = i - n8; }
    float4 x = p[2 * j], y = p[2 * j + 1];
    bf16x8 o;
    o[0] = (bf16)x.x; o[1] = (bf16)x.y; o[2] = (bf16)x.z; o[3] = (bf16)x.w;
    o[4] = (bf16)y.x; o[5] = (bf16)y.y; o[6] = (bf16)y.z; o[7] = (bf16)y.w;
    *(bf16x8*)(dst + 8 * (size_t)j) = o;
}

// ------- all three W [C][C] f32 -> [d][c] bf16 transposed, z-indexed -------
__global__ void transposeW3(const float* __restrict__ W0, const float* __restrict__ W1,
                            const float* __restrict__ W2, bf16* __restrict__ T0,
                            bf16* __restrict__ T1, bf16* __restrict__ T2) {
    __shared__ bf16 t[32][33];
    const int z = blockIdx.z;
    const float* W = z == 0 ? W0 : (z == 1 ? W1 : W2);
    bf16* Wt = z == 0 ? T0 : (z == 1 ? T1 : T2);
    int d0 = blockIdx.x * 32, c0 = blockIdx.y * 32;
    int tx = threadIdx.x, ty = threadIdx.y;  // 32x8
#pragma unroll
    for (int i = 0; i < 4; i++)
        t[ty + 8 * i][tx] = (bf16)W[(size_t)(c0 + ty + 8 * i) * CC + d0 + tx];
    __syncthreads();
#pragma unroll
    for (int i = 0; i < 4; i++)
        Wt[(size_t)(d0 + ty + 8 * i) * CC + c0 + tx] = t[tx][ty + 8 * i];
}

// ------- bq|bk concat + zero the softmax row-sum accumulator (every call) -------
__global__ void prep(const float* __restrict__ a, const float* __restrict__ b,
                     float* __restrict__ bqk, float* __restrict__ rowsum) {
    int i = blockIdx.x * blockDim.x + threadIdx.x;  // 8192 = BZ*NN
    rowsum[i] = 0.f;
    if (i < CC) bqk[i] = a[i];
    else if (i < 2 * CC) bqk[i] = b[i - CC];
}

// ================= BMxBN bf16 B^T GEMM, 4 single-barrier phases/tile =================
// C[m][n] = scale * sum_k A[m][k]*Bt[n][k]  (+ epilogue op)
// EPI: 0 none; 1 col-bias aux[bz*sAux+col]; 2 row-bias aux[row];
//      3 softmax-numerator: C=exp(s-6) bf16 + f32 row-sum atomics aux[bz*sAux+row];
//      4 row-scale: C = s / aux[bz*sAux+row]  (PV normalize).
// Two configs sharing one schedule (r9-proven region-recycle, NB=2, vmcnt(6)):
//   TB=512, 256x256: 8 waves (2Mx4N), wave 128x64, LDS 128KB, 1 block/CU (QK).
//   TB=256, 128x128: 4 waves (2Mx2N), wave 64x64, LDS 64KB, 2 blocks/CU -->
//     cross-block TLP: each SIMD hosts waves of 2 independent blocks, so one
//     block's MFMA covers the other's vmcnt/barrier stalls.
// Uniform staging: every half-tile stage = 16 rows/wave = 2 gloads; steady
// in-flight = 3 half-stages = 6 loads -> vmcnt(6). Region safety: A0 retired
// end-P2, B0/B1 end-P1, A1 end-of-tile (identical proof in both configs).

#define STAGE_A(kt_, hh_)                                                          \
    do {                                                                           \
        int _kt = (kt_);                                                           \
        if (_kt < nkt) {                                                           \
            const bf16* _s = gAs + (size_t)((hh_) * (BM / 2)) * lda +              \
                             (size_t)_kt * 64;                                     \
            bf16* _d = &LA[_kt & 1][((hh_) * (BM / 2) + wid * 16) * 64];           \
            gload_lds16(_s, _d);                                                   \
            gload_lds16(_s + (size_t)8 * lda, _d + 8 * 64);                        \
        }                                                                          \
    } while (0)

#define STAGE_B(kt_, hh_)                                                          \
    do {                                                                           \
        int _kt = (kt_);                                                           \
        if (_kt < nkt) {                                                           \
            const bf16* _s = gBs + (size_t)((hh_) * (BN / 2)) * ldb +              \
                             (size_t)_kt * 64;                                     \
            bf16* _d = &LB[_kt & 1][((hh_) * (BN / 2) + wid * 16) * 64];           \
            gload_lds16(_s, _d);                                                   \
            gload_lds16(_s + (size_t)8 * ldb, _d + 8 * 64);                        \
        }                                                                          \
    } while (0)

#define LDA_FRAG(buf_, mh_)                                                      \
    do {                                                                         \
        _Pragma("unroll") for (int _i = 0; _i < MI; ++_i)                        \
            _Pragma("unroll") for (int _ks = 0; _ks < 2; ++_ks)                  \
                a[_i][_ks] = *(const bf16x8*)&LA[buf_][                          \
                    (wm + (mh_) * (WAVE_M / 2) + _i * 16 + fr) * 64 +            \
                    (((_ks * 4 + hi) ^ lo) * 8)];                                \
    } while (0)

#define LDB_FRAG(buf_, nh_, dst_)                                                \
    do {                                                                         \
        _Pragma("unroll") for (int _j = 0; _j < 2; ++_j)                         \
            _Pragma("unroll") for (int _ks = 0; _ks < 2; ++_ks)                  \
                dst_[_j][_ks] = *(const bf16x8*)&LB[buf_][                       \
                    (wn + (nh_)*32 + _j * 16 + fr) * 64 +                        \
                    (((_ks * 4 + hi) ^ lo) * 8)];                                \
    } while (0)

#define MMQ(mh_, nh_, b_)                                                        \
    do {                                                                         \
        __builtin_amdgcn_s_setprio(1);                                           \
        _Pragma("unroll") for (int _i = 0; _i < MI; ++_i)                        \
            _Pragma("unroll") for (int _j = 0; _j < 2; ++_j)                     \
                _Pragma("unroll") for (int _ks = 0; _ks < 2; ++_ks)              \
                    acc[(mh_)*MI + _i][(nh_)*2 + _j] =                           \
                        __builtin_amdgcn_mfma_f32_16x16x32_bf16(                 \
                            a[_i][_ks], b_[_j][_ks],                             \
                            acc[(mh_)*MI + _i][(nh_)*2 + _j], 0, 0, 0);          \
        __builtin_amdgcn_s_setprio(0);                                           \
    } while (0)

#define VMW(n_) asm volatile("s_waitcnt vmcnt(" #n_ ")" ::: "memory")

template <int TB, int BM, int BN, int EPI, bool OUT_F32>
__global__ __launch_bounds__(TB, 2) void gemm8(
    const bf16* __restrict__ A, int lda,
    const bf16* __restrict__ Bt, int ldb,
    void* __restrict__ Cout, int ldc,
    float* __restrict__ aux, long long sAux, float scale,
    long long sA, long long sB, long long sC, int nkt) {
    constexpr int NW = TB / 64;                 // waves per block
    constexpr int WNW = (TB == 512) ? 4 : 2;    // wave-grid N dim
    constexpr int WAVE_M = BM / 2;              // per-wave M
    constexpr int MI = WAVE_M / 32;             // m-frags per half
    static_assert(BN / WNW == 64, "wave_n must be 64");
    __shared__ __align__(16) bf16 LA[2][BM * 64];
    __shared__ __align__(16) bf16 LB[2][BN * 64];

    // ---- XCD-chunked bijective swizzle (m204)
    const int nx = gridDim.x, ny = gridDim.y;
    const int nwg = nx * ny * gridDim.z;
    const int orig = blockIdx.x + nx * (blockIdx.y + ny * blockIdx.z);
    const int q = nwg >> 3, r = nwg & 7;
    const int xcd = orig & 7, land = orig >> 3;
    const int swz = (xcd < r ? xcd * (q + 1) : r * (q + 1) + (xcd - r) * q) + land;
    const int bx = swz % nx;
    const int tmp = swz / nx;
    const int by = tmp % ny, bz = tmp / ny;

    A += (size_t)bz * sA;
    Bt += (size_t)bz * sB;
    const int m0 = by * BM, n0 = bx * BN;
    const int t = threadIdx.x, wid = t >> 6, lane = t & 63;
    const int wm = (wid / WNW) * WAVE_M, wn = (wid % WNW) * 64;
    const int fr = lane & 15, hi = lane >> 4, lo = lane & 7;
    f32x4 acc[2 * MI][4] = {};

    // staging lane geometry: per gload, wave covers 8 rows x 8 chunks of 16B;
    // source chunk pre-swizzled (chunk ^= row&7), LDS dest linear.
    const int srow = lane >> 3;
    const int schunk = lo ^ srow;
    const bf16* gAs = A + (size_t)(m0 + wid * 16 + srow) * lda + schunk * 8;
    const bf16* gBs = Bt + (size_t)(n0 + wid * 16 + srow) * ldb + schunk * 8;

    // prologue: tile0 fully + tile1 B0,A0,B1; A1(1) comes at kt=0 P0
    STAGE_A(0, 0); STAGE_A(0, 1); STAGE_B(0, 0); STAGE_B(0, 1);
    STAGE_B(1, 0); STAGE_A(1, 0); STAGE_B(1, 1);
    VMW(6);  // tile0 landed, 3 half-stages (6 loads) in flight
    bar();

    bf16x8 a[MI][2], b0[2][2], b1[2][2];
    for (int kt = 0; kt < nkt; ++kt) {
        const int buf = kt & 1;
        // P0: read A-mh0 + B-q0; stage A1(kt+1) -> nbuf (all kt-1 reads done)
        LDA_FRAG(buf, 0);
        LDB_FRAG(buf, 0, b0);
        STAGE_A(kt + 1, 1);
        MMQ(0, 0, b0);
        bar();
        // P1: read B-q1; no stage
        LDB_FRAG(buf, 1, b1);
        MMQ(0, 1, b1);
        bar();
        // P2: read A-mh1; stage B0(kt+2) (B rows 0..BN/2-1 retired end-P1)
        LDA_FRAG(buf, 1);
        STAGE_B(kt + 2, 0);
        MMQ(1, 1, b1);
        bar();
        // P3: stage A0(kt+2) (LA rows 0..BM/2-1 retired end-P2) + B1(kt+2)
        //     (B rows BN/2.. retired end-P1); counted vmcnt after MFMA
        STAGE_A(kt + 2, 0);
        STAGE_B(kt + 2, 1);
        MMQ(1, 0, b0);
        if (kt + 2 < nkt) VMW(6);
        else VMW(0);
        bar();
    }

    // epilogue: C write (C/D map: col=lane&15, row=(lane>>4)*4+reg)
    const int rq = hi * 4;
#pragma unroll
    for (int mh = 0; mh < 2; mh++)
#pragma unroll
        for (int i = 0; i < MI; i++) {
            const int row = m0 + wm + mh * (WAVE_M / 2) + i * 16 + rq;
            float rsum[4] = {0.f, 0.f, 0.f, 0.f};
            float inv[4];
            if (EPI == 4) {
#pragma unroll
                for (int rr = 0; rr < 4; rr++)
                    inv[rr] = 1.f / aux[bz * sAux + row + rr];
            }
#pragma unroll
            for (int nh = 0; nh < 2; nh++)
#pragma unroll
                for (int j = 0; j < 2; j++) {
                    int col = n0 + wn + nh * 32 + j * 16 + fr;
                    float bb = (EPI == 1) ? aux[bz * sAux + col] : 0.f;
                    f32x4 v = acc[mh * MI + i][nh * 2 + j];
#pragma unroll
                    for (int rr = 0; rr < 4; rr++) {
                        float o = v[rr] * scale + bb;
                        if (EPI == 2) o += aux[row + rr];
                        if (EPI == 3) { o = __expf(o - 6.f); rsum[rr] += o; }
                        if (EPI == 4) o *= inv[rr];
                        if (OUT_F32)
                            ((float*)Cout)[(size_t)bz * sC + (size_t)(row + rr) * ldc + col] = o;
                        else
                            ((bf16*)Cout)[(size_t)bz * sC + (size_t)(row + rr) * ldc + col] = (bf16)o;
                    }
                }
            if (EPI == 3) {
                // reduce the partial over the 16 fr-lanes, one f32 atomic/row/wave
#pragma unroll
                for (int rr = 0; rr < 4; rr++) {
                    float s = rsum[rr];
                    s += __shfl_xor(s, 1);
                    s += __shfl_xor(s, 2);
                    s += __shfl_xor(s, 4);
                    s += __shfl_xor(s, 8);
                    if (fr == 0) atomicAdd(&aux[bz * sAux + row + rr], s);
                }
            }
        }
}

extern "C" void kernel_launch(void* const* d_in, const int* in_sizes, int n_in,
                              void* d_out, int out_size, void* d_ws, size_t ws_size,
                              hipStream_t stream) {
    const float* event_f = (const float*)d_in[0];
    const float* img_f   = (const float*)d_in[1];
    const float* Wq = (const float*)d_in[2];
    const float* bq = (const float*)d_in[3];
    const float* Wk = (const float*)d_in[4];
    const float* bk = (const float*)d_in[5];
    const float* Wv = (const float*)d_in[6];
    const float* bv = (const float*)d_in[7];
    float* out = (float*)d_out;

    bf16* ws = (bf16*)d_ws;
    const size_t MC = (size_t)BZ * NN * CC;   // 8388608
    const size_t CCsq = (size_t)CC * CC;      // 1048576
    // layout (bf16 elements); S aliases Ebf+Ibf (dead after VT-GEMM)
    bf16* Ebf  = ws;                          // MC
    bf16* Ibf  = ws + MC;                     // MC
    bf16* S    = ws;                          // 2*MC (reuses Ebf+Ibf)
    size_t off = 2 * MC;
    bf16* Wqkt = ws + off; off += 2 * CCsq;   // Wqt | Wkt contiguous
    bf16* Wvt  = ws + off; off += CCsq;
    bf16* Qb   = ws + off; off += MC;         // [8192][1024]
    bf16* Kb   = ws + off; off += MC;         // [8192][1024]
    bf16* VT   = ws + off; off += MC;         // [B][1024][2048]
    float* bqk = (float*)(ws + off);          // 2048 f32
    float* rowsum = bqk + 2 * CC;             // BZ*NN f32 softmax denominators

    // 1. convert both inputs to bf16 (one dispatch)
    {
        int n8 = (int)(MC / 8);
        cvt2_f32_bf16<<<dim3((2 * n8 + 255) / 256), dim3(256), 0, stream>>>(
            event_f, img_f, Ebf, Ibf, n8);
    }
    // 2. transpose all three weights (one dispatch); concat bq|bk + zero rowsum
    transposeW3<<<dim3(CC / 32, CC / 32, 3), dim3(32, 8), 0, stream>>>(
        Wq, Wk, Wv, Wqkt, Wqkt + CCsq, Wvt);
    prep<<<dim3(BZ * NN / 256), dim3(256), 0, stream>>>(bq, bk, bqk, rowsum);
    // 3. fused Q/K projections (128x128, 2 blocks/CU): z=0 -> Qb; z=1 -> Kb
    gemm8<256, 128, 128, 1, false>
        <<<dim3(CC / 128, (BZ * NN) / 128, 2), dim3(256), 0, stream>>>(
        Ebf, CC, Wqkt, CC, Qb, CC, bqk, CC, 1.f,
        (long long)MC, (long long)CCsq, (long long)MC, CC / 64);
    // 4. VT = Wv^T @ img^T + bv (row-bias), 128x128: per batch M=1024, N=2048
    gemm8<256, 128, 128, 2, false>
        <<<dim3(NN / 128, CC / 128, BZ), dim3(256), 0, stream>>>(
        Wvt, CC, Ibf, CC, VT, NN, (float*)bv, 0, 1.f,
        0, (long long)NN * CC, (long long)CC * NN, CC / 64);
    // 5. S = exp(Q@K^T/32 - 6) + row-sum atomics (proven 512-thr 256x256 path)
    gemm8<512, 256, 256, 3, false>
        <<<dim3(NN / 256, NN / 256, BZ), dim3(512), 0, stream>>>(
        Qb, CC, Kb, CC, S, NN, rowsum, NN, 1.f / 32.f,
        (long long)NN * CC, (long long)NN * CC, (long long)NN * NN, CC / 64);
    // 6. out = (S @ V) / rowsum (128x128, 2 blocks/CU) -> fp32
    gemm8<256, 128, 128, 4, true>
        <<<dim3(CC / 128, NN / 128, BZ), dim3(256), 0, stream>>>(
        S, NN, VT, NN, out, CC, rowsum, NN, 1.f,
        (long long)NN * NN, (long long)CC * NN, (long long)NN * CC, NN / 64);
}